// Round 7
// baseline (123.356 us; speedup 1.0000x reference)
//
#include <hip/hip_runtime.h>
#include <hip/hip_bf16.h>

#define NN 50000
#define NE 312500
#define FIN 256

typedef __attribute__((ext_vector_type(4))) float f32x4;
typedef __attribute__((ext_vector_type(8))) short bf16x8;
typedef __attribute__((ext_vector_type(4))) unsigned short u16x4;

__device__ __forceinline__ float bf2f(unsigned short u) {
  return __builtin_bit_cast(float, ((unsigned int)u) << 16);
}

__global__ void k_zero(int* __restrict__ p, int n) {
  int i = blockIdx.x * 256 + threadIdx.x;
  if (i < n) p[i] = 0;
}

__global__ void k_hist(const int* __restrict__ Ai, int* __restrict__ deg) {
  int e = blockIdx.x * 256 + threadIdx.x;
  if (e < NE) atomicAdd(&deg[Ai[e]], 1);
}

__global__ void k_scan1(const int* __restrict__ deg, int* __restrict__ incl,
                        int* __restrict__ bsum) {
  __shared__ int sm[256];
  int i = blockIdx.x * 256 + threadIdx.x;
  int v = (i < NN) ? deg[i] : 0;
  sm[threadIdx.x] = v;
  __syncthreads();
  for (int s = 1; s < 256; s <<= 1) {
    int t = (threadIdx.x >= (unsigned)s) ? sm[threadIdx.x - s] : 0;
    __syncthreads();
    sm[threadIdx.x] += t;
    __syncthreads();
  }
  if (i < NN) incl[i] = sm[threadIdx.x];
  if (threadIdx.x == 255) bsum[blockIdx.x] = sm[255];
}

__global__ void k_scan2(int* __restrict__ bsum) {
  __shared__ int sm[256];
  int v = (threadIdx.x < 196) ? bsum[threadIdx.x] : 0;
  sm[threadIdx.x] = v;
  __syncthreads();
  for (int s = 1; s < 256; s <<= 1) {
    int t = (threadIdx.x >= (unsigned)s) ? sm[threadIdx.x - s] : 0;
    __syncthreads();
    sm[threadIdx.x] += t;
    __syncthreads();
  }
  if (threadIdx.x < 196) bsum[threadIdx.x] = sm[threadIdx.x] - v;
}

__global__ void k_scan3(const int* __restrict__ incl, const int* __restrict__ deg,
                        const int* __restrict__ bsum, int* __restrict__ offs,
                        int* __restrict__ cursor) {
  int i = blockIdx.x * 256 + threadIdx.x;
  if (i < NN) {
    int o = incl[i] - deg[i] + bsum[blockIdx.x];
    offs[i] = o;
    cursor[i] = o;
  }
}

__global__ void k_scatter(const int* __restrict__ Ai, const int* __restrict__ Aj,
                          int* __restrict__ cursor, int* __restrict__ edst) {
  int e = blockIdx.x * 256 + threadIdx.x;
  if (e < NE) {
    int p = atomicAdd(&cursor[Ai[e]], 1);
    edst[p] = Aj[e];
  }
}

__device__ __forceinline__ bf16x8 cvt8(const float* p) {
  f32x4 a = *(const f32x4*)p;
  f32x4 c = *(const f32x4*)(p + 4);
  bf16x8 r;
  #pragma unroll
  for (int i = 0; i < 4; ++i) {
    r[i]     = (short)__builtin_bit_cast(unsigned short, __float2bfloat16(a[i]));
    r[i + 4] = (short)__builtin_bit_cast(unsigned short, __float2bfloat16(c[i]));
  }
  return r;
}

// Pack Wcat[o][k] (o<256 -> W1 row o; o>=256 -> W2 row o-256) into B-fragment
// order: chunk c = (o/16)*8 + kk; lane l=(lk<<4)|lr holds 8 bf16 of
// (col o16*16+lr, k kk*32+lk*8). 1KB contiguous per chunk.
__global__ __launch_bounds__(256) void k_wconv(const float* __restrict__ W,
                                               unsigned short* __restrict__ WbP) {
  int lane = threadIdx.x & 63, wid = threadIdx.x >> 6;
  int c = blockIdx.x * 4 + wid;           // 256 chunks
  int o16 = c >> 3, kk = c & 7;
  int lr = lane & 15, lk = lane >> 4;
  int o = o16 * 16 + lr;
  int k = kk * 32 + lk * 8;
  const float* src = (o < 256) ? (W + (size_t)o * 512 + k)
                               : (W + (size_t)(o - 256) * 512 + 256 + k);
  *(bf16x8*)(WbP + (size_t)c * 512 + lane * 8) = cvt8(src);
}

// GEMM: Yb[row][col'] = bf16( x[row] @ [W1|W2]^T ), col' PERMUTED:
// within stripe wid (128 cols): col' = lr*8 + n, true col = n*16 + lr.
// Block: 32 rows x 512 cols; 4 waves = 4 col-stripes; T3 2-phase:
// A-tile (16KB frag-order LDS) staged once; B (32KB/K-step) double-buffered
// via global_load_lds, issued before ds_read+MFMA, one barrier per step.
__global__ __launch_bounds__(256, 2) void k_gemm(
    const float* __restrict__ x, const unsigned short* __restrict__ WbP,
    unsigned short* __restrict__ Yb) {
  __shared__ unsigned short lds[40960];   // 80KB: [0,8192)=A, then 2x16384 B bufs
  const int tid = threadIdx.x;
  const int lane = tid & 63, wid = tid >> 6;
  const int lr = lane & 15, lk = lane >> 4;
  const int n0 = blockIdx.x * 32;
  unsigned short* buf0 = lds + 8192;
  unsigned short* buf1 = lds + 24576;

  // issue B stage for t=0 (DMA runs under A staging)
  #pragma unroll
  for (int i = 0; i < 8; ++i) {
    int cw = wid * 8 + i;
    __builtin_amdgcn_global_load_lds(
        (const __attribute__((address_space(1))) void*)(WbP + ((size_t)cw * 8 + 0) * 512 + lane * 8),
        (__attribute__((address_space(3))) void*)(buf0 + cw * 512 + lane * 8), 16, 0, 0);
  }
  // stage A: 32 rows x 256 k, fp32 -> bf16 frag order (chunks (row>>4)*8+kk)
  #pragma unroll
  for (int it = 0; it < 4; ++it) {
    int i = it * 256 + tid;          // 0..1023
    int row = i >> 5, seg = i & 31;
    int g = n0 + row;
    bf16x8 v = {0, 0, 0, 0, 0, 0, 0, 0};
    if (g < NN) v = cvt8(x + (size_t)g * FIN + seg * 8);
    *(bf16x8*)(lds + ((row >> 4) * 8 + (seg >> 2)) * 512 + ((seg & 3) * 16 + (row & 15)) * 8) = v;
  }
  __syncthreads();

  f32x4 acc[2][8];
  #pragma unroll
  for (int m = 0; m < 2; ++m)
    #pragma unroll
    for (int n = 0; n < 8; ++n) acc[m][n] = (f32x4){0.f, 0.f, 0.f, 0.f};

  #pragma unroll
  for (int t = 0; t < 8; ++t) {
    if (t < 7) {   // stage next K-step's B into the other buffer
      unsigned short* dst = ((t + 1) & 1) ? buf1 : buf0;
      #pragma unroll
      for (int i = 0; i < 8; ++i) {
        int cw = wid * 8 + i;
        __builtin_amdgcn_global_load_lds(
            (const __attribute__((address_space(1))) void*)(WbP + ((size_t)cw * 8 + t + 1) * 512 + lane * 8),
            (__attribute__((address_space(3))) void*)(dst + cw * 512 + lane * 8), 16, 0, 0);
      }
    }
    const unsigned short* bq = (t & 1) ? buf1 : buf0;
    bf16x8 af0 = *(const bf16x8*)(lds + (0 * 8 + t) * 512 + lane * 8);
    bf16x8 af1 = *(const bf16x8*)(lds + (1 * 8 + t) * 512 + lane * 8);
    bf16x8 bfr[8];
    #pragma unroll
    for (int n = 0; n < 8; ++n)
      bfr[n] = *(const bf16x8*)(bq + (wid * 8 + n) * 512 + lane * 8);
    #pragma unroll
    for (int n = 0; n < 8; ++n) {
      acc[0][n] = __builtin_amdgcn_mfma_f32_16x16x32_bf16(af0, bfr[n], acc[0][n], 0, 0, 0);
      acc[1][n] = __builtin_amdgcn_mfma_f32_16x16x32_bf16(af1, bfr[n], acc[1][n], 0, 0, 0);
    }
    if (t < 7) __syncthreads();   // drains DMA (vmcnt0) + LDS reads; flips buffers
  }

  // epilogue: direct permuted bf16x8 stores (no LDS, no transpose)
  #pragma unroll
  for (int m = 0; m < 2; ++m) {
    #pragma unroll
    for (int r = 0; r < 4; ++r) {
      int rowg = n0 + m * 16 + lk * 4 + r;
      if (rowg < NN) {
        bf16x8 v;
        #pragma unroll
        for (int n = 0; n < 8; ++n)
          v[n] = (short)__builtin_bit_cast(unsigned short, __float2bfloat16(acc[m][n][r]));
        *(bf16x8*)(Yb + (size_t)rowg * 512 + wid * 128 + lr * 8) = v;
      }
    }
  }
}

// One wave per node: out[n] = deg[n]*(Y1b[n]+b) + sum_{CSR} Y2b[j].
// Yb is column-permuted; accumulate permuted, unpermute via 1KB/wave LDS.
// Edge loop unrolled 8-wide (8 independent 512B row loads in flight).
__global__ __launch_bounds__(256) void k_epi(
    const unsigned short* __restrict__ Yb, const int* __restrict__ offs,
    const int* __restrict__ deg, const int* __restrict__ edst,
    const float* __restrict__ bias, float* __restrict__ out) {
  __shared__ float sm[1024];
  int wid = threadIdx.x >> 6;
  int lane = threadIdx.x & 63;
  int n = blockIdx.x * 4 + wid;
  if (n >= NN) return;
  int o = offs[n];
  int c = deg[n];
  const unsigned short* Y2 = Yb + 256 + (size_t)lane * 4;
  f32x4 a0 = {0.f,0.f,0.f,0.f}, a1 = a0, a2 = a0, a3 = a0, a4 = a0, a5 = a0, a6 = a0, a7 = a0;
  int e = 0;
  for (; e + 8 <= c; e += 8) {
    int j0 = edst[o+e],   j1 = edst[o+e+1], j2 = edst[o+e+2], j3 = edst[o+e+3];
    int j4 = edst[o+e+4], j5 = edst[o+e+5], j6 = edst[o+e+6], j7 = edst[o+e+7];
    u16x4 v0 = *(const u16x4*)(Y2 + (size_t)j0 * 512);
    u16x4 v1 = *(const u16x4*)(Y2 + (size_t)j1 * 512);
    u16x4 v2 = *(const u16x4*)(Y2 + (size_t)j2 * 512);
    u16x4 v3 = *(const u16x4*)(Y2 + (size_t)j3 * 512);
    u16x4 v4 = *(const u16x4*)(Y2 + (size_t)j4 * 512);
    u16x4 v5 = *(const u16x4*)(Y2 + (size_t)j5 * 512);
    u16x4 v6 = *(const u16x4*)(Y2 + (size_t)j6 * 512);
    u16x4 v7 = *(const u16x4*)(Y2 + (size_t)j7 * 512);
    #pragma unroll
    for (int i = 0; i < 4; ++i) {
      a0[i] += bf2f(v0[i]); a1[i] += bf2f(v1[i]); a2[i] += bf2f(v2[i]); a3[i] += bf2f(v3[i]);
      a4[i] += bf2f(v4[i]); a5[i] += bf2f(v5[i]); a6[i] += bf2f(v6[i]); a7[i] += bf2f(v7[i]);
    }
  }
  if (e + 4 <= c) {
    int j0 = edst[o+e], j1 = edst[o+e+1], j2 = edst[o+e+2], j3 = edst[o+e+3];
    u16x4 v0 = *(const u16x4*)(Y2 + (size_t)j0 * 512);
    u16x4 v1 = *(const u16x4*)(Y2 + (size_t)j1 * 512);
    u16x4 v2 = *(const u16x4*)(Y2 + (size_t)j2 * 512);
    u16x4 v3 = *(const u16x4*)(Y2 + (size_t)j3 * 512);
    #pragma unroll
    for (int i = 0; i < 4; ++i) {
      a0[i] += bf2f(v0[i]); a1[i] += bf2f(v1[i]); a2[i] += bf2f(v2[i]); a3[i] += bf2f(v3[i]);
    }
    e += 4;
  }
  if (e + 2 <= c) {
    int j0 = edst[o+e], j1 = edst[o+e+1];
    u16x4 v0 = *(const u16x4*)(Y2 + (size_t)j0 * 512);
    u16x4 v1 = *(const u16x4*)(Y2 + (size_t)j1 * 512);
    #pragma unroll
    for (int i = 0; i < 4; ++i) { a0[i] += bf2f(v0[i]); a1[i] += bf2f(v1[i]); }
    e += 2;
  }
  if (e < c) {
    int j0 = edst[o+e];
    u16x4 v0 = *(const u16x4*)(Y2 + (size_t)j0 * 512);
    #pragma unroll
    for (int i = 0; i < 4; ++i) a0[i] += bf2f(v0[i]);
  }
  u16x4 y1 = *(const u16x4*)(Yb + (size_t)n * 512 + lane * 4);
  float dg = (float)c;
  float* Wm = sm + wid * 256;
  #pragma unroll
  for (int i = 0; i < 4; ++i) {
    int p = lane * 4 + i;                                   // permuted col
    int tc = (p >> 7) * 128 + (p & 7) * 16 + ((p >> 3) & 15);  // true col
    float as = ((a0[i] + a1[i]) + (a2[i] + a3[i])) + ((a4[i] + a5[i]) + (a6[i] + a7[i]));
    Wm[tc] = dg * (bf2f(y1[i]) + bias[tc]) + as;
  }
  asm volatile("s_waitcnt lgkmcnt(0)" ::: "memory");   // wave-lockstep: all 64 lanes' writes done
  f32x4 res = *(const f32x4*)(Wm + lane * 4);
  __builtin_nontemporal_store(res, (f32x4*)out + (size_t)n * 64 + lane);
}

extern "C" void kernel_launch(void* const* d_in, const int* in_sizes, int n_in,
                              void* d_out, int out_size, void* d_ws, size_t ws_size,
                              hipStream_t stream) {
  const float* x = (const float*)d_in[0];
  const float* W = (const float*)d_in[1];
  const float* b = (const float*)d_in[2];
  const int* Ai = (const int*)d_in[3];
  const int* Aj = (const int*)d_in[4];
  float* out = (float*)d_out;

  int* ip = (int*)d_ws;
  int* deg    = ip;            // 50048 (zeroed by k_zero, padded)
  int* incl   = ip + 50048;
  int* offs   = ip + 100096;
  int* cursor = ip + 150144;
  int* bsum   = ip + 200192;   // 256
  int* edst   = ip + 200448;   // 312576
  unsigned short* WbP = (unsigned short*)(ip + 513024);   // 131072 bf16 = 256KB
  unsigned short* Yb  = (unsigned short*)(ip + 578560);   // 50048*512 bf16 = 51.2MB

  k_zero<<<196, 256, 0, stream>>>(deg, 50048);
  k_hist<<<1221, 256, 0, stream>>>(Ai, deg);
  k_scan1<<<196, 256, 0, stream>>>(deg, incl, bsum);
  k_scan2<<<1, 256, 0, stream>>>(bsum);
  k_scan3<<<196, 256, 0, stream>>>(incl, deg, bsum, offs, cursor);
  k_scatter<<<1221, 256, 0, stream>>>(Ai, Aj, cursor, edst);
  k_wconv<<<64, 256, 0, stream>>>(W, WbP);
  k_gemm<<<1564, 256, 0, stream>>>(x, WbP, Yb);
  k_epi<<<12500, 256, 0, stream>>>(Yb, offs, deg, edst, b, out);
}

// Round 8
// 116.290 us; speedup vs baseline: 1.0608x; 1.0608x over previous
//
#include <hip/hip_runtime.h>
#include <hip/hip_bf16.h>

#define NN 50000
#define NE 312500
#define FIN 256

typedef __attribute__((ext_vector_type(4))) float f32x4;
typedef __attribute__((ext_vector_type(8))) short bf16x8;
typedef __attribute__((ext_vector_type(4))) unsigned short u16x4;

__device__ __forceinline__ float bf2f(unsigned short u) {
  return __builtin_bit_cast(float, ((unsigned int)u) << 16);
}

__global__ void k_hist(const int* __restrict__ Ai, int* __restrict__ deg) {
  int e = blockIdx.x * 256 + threadIdx.x;
  if (e < NE) atomicAdd(&deg[Ai[e]], 1);
}

__global__ void k_scan1(const int* __restrict__ deg, int* __restrict__ incl,
                        int* __restrict__ bsum) {
  __shared__ int sm[256];
  int i = blockIdx.x * 256 + threadIdx.x;
  int v = (i < NN) ? deg[i] : 0;
  sm[threadIdx.x] = v;
  __syncthreads();
  for (int s = 1; s < 256; s <<= 1) {
    int t = (threadIdx.x >= (unsigned)s) ? sm[threadIdx.x - s] : 0;
    __syncthreads();
    sm[threadIdx.x] += t;
    __syncthreads();
  }
  if (i < NN) incl[i] = sm[threadIdx.x];
  if (threadIdx.x == 255) bsum[blockIdx.x] = sm[255];
}

__global__ void k_scan2(int* __restrict__ bsum) {
  __shared__ int sm[256];
  int v = (threadIdx.x < 196) ? bsum[threadIdx.x] : 0;
  sm[threadIdx.x] = v;
  __syncthreads();
  for (int s = 1; s < 256; s <<= 1) {
    int t = (threadIdx.x >= (unsigned)s) ? sm[threadIdx.x - s] : 0;
    __syncthreads();
    sm[threadIdx.x] += t;
    __syncthreads();
  }
  if (threadIdx.x < 196) bsum[threadIdx.x] = sm[threadIdx.x] - v;
}

__global__ void k_scan3(const int* __restrict__ incl, const int* __restrict__ deg,
                        const int* __restrict__ bsum, int* __restrict__ offs,
                        int* __restrict__ cursor) {
  int i = blockIdx.x * 256 + threadIdx.x;
  if (i < NN) {
    int o = incl[i] - deg[i] + bsum[blockIdx.x];
    offs[i] = o;
    cursor[i] = o;
  }
}

__global__ void k_scatter(const int* __restrict__ Ai, const int* __restrict__ Aj,
                          int* __restrict__ cursor, int* __restrict__ edst) {
  int e = blockIdx.x * 256 + threadIdx.x;
  if (e < NE) {
    int p = atomicAdd(&cursor[Ai[e]], 1);
    edst[p] = Aj[e];
  }
}

__device__ __forceinline__ bf16x8 cvt8(const float* p) {
  f32x4 a = *(const f32x4*)p;
  f32x4 c = *(const f32x4*)(p + 4);
  bf16x8 r;
  #pragma unroll
  for (int i = 0; i < 4; ++i) {
    r[i]     = (short)__builtin_bit_cast(unsigned short, __float2bfloat16(a[i]));
    r[i + 4] = (short)__builtin_bit_cast(unsigned short, __float2bfloat16(c[i]));
  }
  return r;
}

// Fused: blocks 0..63 pack W into B-fragment order; blocks 64..259 zero deg.
// WbP chunk c = (o/16)*8 + kk; lane l=(lk<<4)|lr holds 8 bf16 of
// (col o16*16+lr, k kk*32+lk*8). 1KB contiguous per chunk.
__global__ __launch_bounds__(256) void k_wz(const float* __restrict__ W,
                                            unsigned short* __restrict__ WbP,
                                            int* __restrict__ deg) {
  if (blockIdx.x >= 64) {
    int i = (blockIdx.x - 64) * 256 + threadIdx.x;
    if (i < 50048) deg[i] = 0;
    return;
  }
  int lane = threadIdx.x & 63, wid = threadIdx.x >> 6;
  int c = blockIdx.x * 4 + wid;           // 256 chunks
  int o16 = c >> 3, kk = c & 7;
  int lr = lane & 15, lk = lane >> 4;
  int o = o16 * 16 + lr;
  int k = kk * 32 + lk * 8;
  const float* src = (o < 256) ? (W + (size_t)o * 512 + k)
                               : (W + (size_t)(o - 256) * 512 + 256 + k);
  *(bf16x8*)(WbP + (size_t)c * 512 + lane * 8) = cvt8(src);
}

// GEMM: Yb[row][col'] = bf16( x[row] @ [W1|W2]^T ), col' PERMUTED:
// within stripe wid: col' = lr*8 + n, true col = n*16 + lr.
// Block: 32 rows x 512 cols; 4 waves = 4 col-stripes.
// A: XOR-swizzled frag-order LDS (16KB), staged once, one raw barrier.
// B: wave-PRIVATE 8KB slices, double-buffered via global_load_lds with
// counted s_waitcnt vmcnt(8) — NO barriers in the K-loop (T3/T4).
__global__ __launch_bounds__(256) void k_gemm(
    const float* __restrict__ x, const unsigned short* __restrict__ WbP,
    unsigned short* __restrict__ Yb) {
  __shared__ __align__(16) unsigned short lds[40960];  // 80KB: A 16KB, B0/B1 32KB
  const int tid = threadIdx.x;
  const int lane = tid & 63, wid = tid >> 6;
  const int lr = lane & 15, lk = lane >> 4;
  const int n0 = blockIdx.x * 32;
  unsigned short* A  = lds;
  unsigned short* B0 = lds + 8192;
  unsigned short* B1 = lds + 24576;

  // issue B(0) DMA — runs under A staging
  #pragma unroll
  for (int i = 0; i < 8; ++i) {
    int cw = wid * 8 + i;
    __builtin_amdgcn_global_load_lds(
        (const __attribute__((address_space(1))) void*)(WbP + ((size_t)cw * 8 + 0) * 512 + lane * 8),
        (__attribute__((address_space(3))) void*)(B0 + cw * 512 + lane * 8), 16, 0, 0);
  }
  // stage A: 32 rows x 256 k, fp32 -> bf16, frag order, XOR-swizzled (4-way max)
  #pragma unroll
  for (int it = 0; it < 4; ++it) {
    int i = it * 256 + tid;          // 0..1023
    int row = i >> 5, seg = i & 31;
    int g = n0 + row;
    bf16x8 v = {0, 0, 0, 0, 0, 0, 0, 0};
    if (g < NN) v = cvt8(x + (size_t)g * FIN + seg * 8);
    int u = ((row >> 4) * 8 + (seg >> 2)) * 512 +
            ((((seg & 3) * 16 + (row & 15)) * 8) ^ ((seg & 7) << 3));
    *(bf16x8*)(A + u) = v;
  }
  asm volatile("s_waitcnt lgkmcnt(0)" ::: "memory");
  __builtin_amdgcn_sched_barrier(0);
  __builtin_amdgcn_s_barrier();          // raw: no vmcnt drain of B-DMA
  __builtin_amdgcn_sched_barrier(0);

  f32x4 acc[2][8];
  #pragma unroll
  for (int m = 0; m < 2; ++m)
    #pragma unroll
    for (int n = 0; n < 8; ++n) acc[m][n] = (f32x4){0.f, 0.f, 0.f, 0.f};

  #pragma unroll
  for (int t = 0; t < 8; ++t) {
    if (t < 7) {   // issue next K-step's B into the other (wave-private) buffer
      unsigned short* dst = ((t + 1) & 1) ? B1 : B0;
      #pragma unroll
      for (int i = 0; i < 8; ++i) {
        int cw = wid * 8 + i;
        __builtin_amdgcn_global_load_lds(
            (const __attribute__((address_space(1))) void*)(WbP + ((size_t)cw * 8 + t + 1) * 512 + lane * 8),
            (__attribute__((address_space(3))) void*)(dst + cw * 512 + lane * 8), 16, 0, 0);
      }
      asm volatile("s_waitcnt vmcnt(8)" ::: "memory");   // B(t) landed; B(t+1) in flight
    } else {
      asm volatile("s_waitcnt vmcnt(0)" ::: "memory");
    }
    __builtin_amdgcn_sched_barrier(0);
    const unsigned short* bq = (t & 1) ? B1 : B0;
    const int c0 = t, c1 = 8 + t;
    bf16x8 af0 = *(const bf16x8*)(A + c0 * 512 + ((lane * 8) ^ (((c0 & 1) << 5) | (lk << 3))));
    bf16x8 af1 = *(const bf16x8*)(A + c1 * 512 + ((lane * 8) ^ (((c1 & 1) << 5) | (lk << 3))));
    bf16x8 bfr[8];
    #pragma unroll
    for (int n = 0; n < 8; ++n)
      bfr[n] = *(const bf16x8*)(bq + (wid * 8 + n) * 512 + lane * 8);
    #pragma unroll
    for (int n = 0; n < 8; ++n) {
      acc[0][n] = __builtin_amdgcn_mfma_f32_16x16x32_bf16(af0, bfr[n], acc[0][n], 0, 0, 0);
      acc[1][n] = __builtin_amdgcn_mfma_f32_16x16x32_bf16(af1, bfr[n], acc[1][n], 0, 0, 0);
    }
  }

  // epilogue: direct permuted bf16x8 stores (no LDS, no transpose)
  #pragma unroll
  for (int m = 0; m < 2; ++m) {
    #pragma unroll
    for (int r = 0; r < 4; ++r) {
      int rowg = n0 + m * 16 + lk * 4 + r;
      if (rowg < NN) {
        bf16x8 v;
        #pragma unroll
        for (int n = 0; n < 8; ++n)
          v[n] = (short)__builtin_bit_cast(unsigned short, __float2bfloat16(acc[m][n][r]));
        *(bf16x8*)(Yb + (size_t)rowg * 512 + wid * 128 + lr * 8) = v;
      }
    }
  }
}

// One wave per node: out[n] = deg[n]*(Y1b[n]+b) + sum_{CSR} Y2b[j].
// Yb is column-permuted; accumulate permuted, unpermute via 1KB/wave LDS.
__global__ __launch_bounds__(256) void k_epi(
    const unsigned short* __restrict__ Yb, const int* __restrict__ offs,
    const int* __restrict__ deg, const int* __restrict__ edst,
    const float* __restrict__ bias, float* __restrict__ out) {
  __shared__ float sm[1024];
  int wid = threadIdx.x >> 6;
  int lane = threadIdx.x & 63;
  int n = blockIdx.x * 4 + wid;
  if (n >= NN) return;
  int o = offs[n];
  int c = deg[n];
  const unsigned short* Y2 = Yb + 256 + (size_t)lane * 4;
  f32x4 a0 = {0.f,0.f,0.f,0.f}, a1 = a0, a2 = a0, a3 = a0, a4 = a0, a5 = a0, a6 = a0, a7 = a0;
  int e = 0;
  for (; e + 8 <= c; e += 8) {
    int j0 = edst[o+e],   j1 = edst[o+e+1], j2 = edst[o+e+2], j3 = edst[o+e+3];
    int j4 = edst[o+e+4], j5 = edst[o+e+5], j6 = edst[o+e+6], j7 = edst[o+e+7];
    u16x4 v0 = *(const u16x4*)(Y2 + (size_t)j0 * 512);
    u16x4 v1 = *(const u16x4*)(Y2 + (size_t)j1 * 512);
    u16x4 v2 = *(const u16x4*)(Y2 + (size_t)j2 * 512);
    u16x4 v3 = *(const u16x4*)(Y2 + (size_t)j3 * 512);
    u16x4 v4 = *(const u16x4*)(Y2 + (size_t)j4 * 512);
    u16x4 v5 = *(const u16x4*)(Y2 + (size_t)j5 * 512);
    u16x4 v6 = *(const u16x4*)(Y2 + (size_t)j6 * 512);
    u16x4 v7 = *(const u16x4*)(Y2 + (size_t)j7 * 512);
    #pragma unroll
    for (int i = 0; i < 4; ++i) {
      a0[i] += bf2f(v0[i]); a1[i] += bf2f(v1[i]); a2[i] += bf2f(v2[i]); a3[i] += bf2f(v3[i]);
      a4[i] += bf2f(v4[i]); a5[i] += bf2f(v5[i]); a6[i] += bf2f(v6[i]); a7[i] += bf2f(v7[i]);
    }
  }
  if (e + 4 <= c) {
    int j0 = edst[o+e], j1 = edst[o+e+1], j2 = edst[o+e+2], j3 = edst[o+e+3];
    u16x4 v0 = *(const u16x4*)(Y2 + (size_t)j0 * 512);
    u16x4 v1 = *(const u16x4*)(Y2 + (size_t)j1 * 512);
    u16x4 v2 = *(const u16x4*)(Y2 + (size_t)j2 * 512);
    u16x4 v3 = *(const u16x4*)(Y2 + (size_t)j3 * 512);
    #pragma unroll
    for (int i = 0; i < 4; ++i) {
      a0[i] += bf2f(v0[i]); a1[i] += bf2f(v1[i]); a2[i] += bf2f(v2[i]); a3[i] += bf2f(v3[i]);
    }
    e += 4;
  }
  if (e + 2 <= c) {
    int j0 = edst[o+e], j1 = edst[o+e+1];
    u16x4 v0 = *(const u16x4*)(Y2 + (size_t)j0 * 512);
    u16x4 v1 = *(const u16x4*)(Y2 + (size_t)j1 * 512);
    #pragma unroll
    for (int i = 0; i < 4; ++i) { a0[i] += bf2f(v0[i]); a1[i] += bf2f(v1[i]); }
    e += 2;
  }
  if (e < c) {
    int j0 = edst[o+e];
    u16x4 v0 = *(const u16x4*)(Y2 + (size_t)j0 * 512);
    #pragma unroll
    for (int i = 0; i < 4; ++i) a0[i] += bf2f(v0[i]);
  }
  u16x4 y1 = *(const u16x4*)(Yb + (size_t)n * 512 + lane * 4);
  float dg = (float)c;
  float* Wm = sm + wid * 256;
  #pragma unroll
  for (int i = 0; i < 4; ++i) {
    int p = lane * 4 + i;                                      // permuted col
    int tc = (p >> 7) * 128 + (p & 7) * 16 + ((p >> 3) & 15);  // true col
    float as = ((a0[i] + a1[i]) + (a2[i] + a3[i])) + ((a4[i] + a5[i]) + (a6[i] + a7[i]));
    Wm[tc] = dg * (bf2f(y1[i]) + bias[tc]) + as;
  }
  asm volatile("s_waitcnt lgkmcnt(0)" ::: "memory");   // wave-lockstep unpermute
  f32x4 res = *(const f32x4*)(Wm + lane * 4);
  __builtin_nontemporal_store(res, (f32x4*)out + (size_t)n * 64 + lane);
}

extern "C" void kernel_launch(void* const* d_in, const int* in_sizes, int n_in,
                              void* d_out, int out_size, void* d_ws, size_t ws_size,
                              hipStream_t stream) {
  const float* x = (const float*)d_in[0];
  const float* W = (const float*)d_in[1];
  const float* b = (const float*)d_in[2];
  const int* Ai = (const int*)d_in[3];
  const int* Aj = (const int*)d_in[4];
  float* out = (float*)d_out;

  int* ip = (int*)d_ws;
  int* deg    = ip;            // 50048 (zeroed by k_wz, padded)
  int* incl   = ip + 50048;
  int* offs   = ip + 100096;
  int* cursor = ip + 150144;
  int* bsum   = ip + 200192;   // 256
  int* edst   = ip + 200448;   // 312576
  unsigned short* WbP = (unsigned short*)(ip + 513024);   // 131072 bf16 = 256KB
  unsigned short* Yb  = (unsigned short*)(ip + 578560);   // 50048*512 bf16 = 51.2MB

  k_wz<<<260, 256, 0, stream>>>(W, WbP, deg);
  k_hist<<<1221, 256, 0, stream>>>(Ai, deg);
  k_scan1<<<196, 256, 0, stream>>>(deg, incl, bsum);
  k_scan2<<<1, 256, 0, stream>>>(bsum);
  k_scan3<<<196, 256, 0, stream>>>(incl, deg, bsum, offs, cursor);
  k_scatter<<<1221, 256, 0, stream>>>(Ai, Aj, cursor, edst);
  k_gemm<<<1564, 256, 0, stream>>>(x, WbP, Yb);
  k_epi<<<12500, 256, 0, stream>>>(Yb, offs, deg, edst, b, out);
}

// Round 9
// 115.827 us; speedup vs baseline: 1.0650x; 1.0040x over previous
//
#include <hip/hip_runtime.h>
#include <hip/hip_bf16.h>

#define NN 50000
#define NE 312500
#define FIN 256

typedef __attribute__((ext_vector_type(4))) float f32x4;
typedef __attribute__((ext_vector_type(8))) short bf16x8;
typedef __attribute__((ext_vector_type(4))) unsigned short u16x4;

__device__ __forceinline__ float bf2f(unsigned short u) {
  return __builtin_bit_cast(float, ((unsigned int)u) << 16);
}

__global__ void k_hist(const int* __restrict__ Ai, int* __restrict__ deg) {
  int e = blockIdx.x * 256 + threadIdx.x;
  if (e < NE) atomicAdd(&deg[Ai[e]], 1);
}

__global__ void k_scan1(const int* __restrict__ deg, int* __restrict__ incl,
                        int* __restrict__ bsum) {
  __shared__ int sm[256];
  int i = blockIdx.x * 256 + threadIdx.x;
  int v = (i < NN) ? deg[i] : 0;
  sm[threadIdx.x] = v;
  __syncthreads();
  for (int s = 1; s < 256; s <<= 1) {
    int t = (threadIdx.x >= (unsigned)s) ? sm[threadIdx.x - s] : 0;
    __syncthreads();
    sm[threadIdx.x] += t;
    __syncthreads();
  }
  if (i < NN) incl[i] = sm[threadIdx.x];
  if (threadIdx.x == 255) bsum[blockIdx.x] = sm[255];
}

__global__ void k_scan2(int* __restrict__ bsum) {
  __shared__ int sm[256];
  int v = (threadIdx.x < 196) ? bsum[threadIdx.x] : 0;
  sm[threadIdx.x] = v;
  __syncthreads();
  for (int s = 1; s < 256; s <<= 1) {
    int t = (threadIdx.x >= (unsigned)s) ? sm[threadIdx.x - s] : 0;
    __syncthreads();
    sm[threadIdx.x] += t;
    __syncthreads();
  }
  if (threadIdx.x < 196) bsum[threadIdx.x] = sm[threadIdx.x] - v;
}

__global__ void k_scan3(const int* __restrict__ incl, const int* __restrict__ deg,
                        const int* __restrict__ bsum, int* __restrict__ offs,
                        int* __restrict__ cursor) {
  int i = blockIdx.x * 256 + threadIdx.x;
  if (i < NN) {
    int o = incl[i] - deg[i] + bsum[blockIdx.x];
    offs[i] = o;
    cursor[i] = o;
  }
}

__global__ void k_scatter(const int* __restrict__ Ai, const int* __restrict__ Aj,
                          int* __restrict__ cursor, int* __restrict__ edst) {
  int e = blockIdx.x * 256 + threadIdx.x;
  if (e < NE) {
    int p = atomicAdd(&cursor[Ai[e]], 1);
    edst[p] = Aj[e];
  }
}

__device__ __forceinline__ bf16x8 cvt8(const float* p) {
  f32x4 a = *(const f32x4*)p;
  f32x4 c = *(const f32x4*)(p + 4);
  bf16x8 r;
  #pragma unroll
  for (int i = 0; i < 4; ++i) {
    r[i]     = (short)__builtin_bit_cast(unsigned short, __float2bfloat16(a[i]));
    r[i + 4] = (short)__builtin_bit_cast(unsigned short, __float2bfloat16(c[i]));
  }
  return r;
}

// Fused: blocks 0..63 pack W into B-fragment order; blocks 64..259 zero deg.
// WbP chunk c = (o/16)*8 + kk; lane l=(lk<<4)|lr holds 8 bf16 of
// (col o16*16+lr, k kk*32+lk*8). 1KB contiguous per chunk.
__global__ __launch_bounds__(256) void k_wz(const float* __restrict__ W,
                                            unsigned short* __restrict__ WbP,
                                            int* __restrict__ deg) {
  if (blockIdx.x >= 64) {
    int i = (blockIdx.x - 64) * 256 + threadIdx.x;
    if (i < 50048) deg[i] = 0;
    return;
  }
  int lane = threadIdx.x & 63, wid = threadIdx.x >> 6;
  int c = blockIdx.x * 4 + wid;           // 256 chunks
  int o16 = c >> 3, kk = c & 7;
  int lr = lane & 15, lk = lane >> 4;
  int o = o16 * 16 + lr;
  int k = kk * 32 + lk * 8;
  const float* src = (o < 256) ? (W + (size_t)o * 512 + k)
                               : (W + (size_t)(o - 256) * 512 + 256 + k);
  *(bf16x8*)(WbP + (size_t)c * 512 + lane * 8) = cvt8(src);
}

// GEMM: Yb[row][q] = bf16( x[row] @ [W1|W2]^T ), q PERMUTED:
// q = h*256 + w*64 + lr*4 + n  <->  true col = h*256 + w*64 + n*16 + lr.
// Grid (391,2): block = 128 rows x 256 cols (half h); 4 waves = 4x 64-col
// stripes. B panel (64 cols x K=256) lives in 128 VGPRs per wave, loaded
// once from L2. A staged once in 64KB swizzled LDS. Inner loop is pure
// ds_read + MFMA — no global ops, no waits, no barriers.
__global__ __launch_bounds__(256, 2) void k_gemm(
    const float* __restrict__ x, const unsigned short* __restrict__ WbP,
    unsigned short* __restrict__ Yb) {
  __shared__ __align__(16) unsigned short A[32768];   // 64KB: 64 chunks x 512
  const int tid = threadIdx.x;
  const int lane = tid & 63, wid = tid >> 6;
  const int lr = lane & 15, lk = lane >> 4;
  const int n0 = blockIdx.x * 128;
  const int h = blockIdx.y;
  const int o16b = h * 16 + wid * 4;    // this wave's 4 col16 frags

  // B panel -> registers (32 frags = 128 VGPR), L2-resident source
  bf16x8 bfr[8][4];
  #pragma unroll
  for (int kk = 0; kk < 8; ++kk)
    #pragma unroll
    for (int n = 0; n < 4; ++n)
      bfr[kk][n] = *(const bf16x8*)(WbP + ((size_t)(o16b + n) * 8 + kk) * 512 + lane * 8);

  // stage A: 128 rows x 256 k, fp32 -> bf16, frag order, XOR-swizzled
  #pragma unroll
  for (int it = 0; it < 16; ++it) {
    int i = it * 256 + tid;          // 0..4095
    int row = i >> 5, seg = i & 31;
    int g = n0 + row;
    bf16x8 v = {0, 0, 0, 0, 0, 0, 0, 0};
    if (g < NN) v = cvt8(x + (size_t)g * FIN + seg * 8);
    int u = ((row >> 4) * 8 + (seg >> 2)) * 512 +
            ((((seg & 3) * 16 + (row & 15)) * 8) ^ ((seg & 7) << 3));
    *(bf16x8*)(A + u) = v;
  }
  __syncthreads();

  // 4 row-subtiles of 32 rows; per subtile: 8 kk x (2 ds_read + 8 MFMA)
  #pragma unroll
  for (int s = 0; s < 4; ++s) {
    f32x4 acc[2][4];
    #pragma unroll
    for (int m = 0; m < 2; ++m)
      #pragma unroll
      for (int n = 0; n < 4; ++n) acc[m][n] = (f32x4){0.f, 0.f, 0.f, 0.f};
    #pragma unroll
    for (int kk = 0; kk < 8; ++kk) {
      int sw = (lane * 8) ^ (((kk & 1) << 5) | (lk << 3));
      bf16x8 af0 = *(const bf16x8*)(A + ((2 * s + 0) * 8 + kk) * 512 + sw);
      bf16x8 af1 = *(const bf16x8*)(A + ((2 * s + 1) * 8 + kk) * 512 + sw);
      #pragma unroll
      for (int n = 0; n < 4; ++n) {
        acc[0][n] = __builtin_amdgcn_mfma_f32_16x16x32_bf16(af0, bfr[kk][n], acc[0][n], 0, 0, 0);
        acc[1][n] = __builtin_amdgcn_mfma_f32_16x16x32_bf16(af1, bfr[kk][n], acc[1][n], 0, 0, 0);
      }
    }
    // store: rows n0+s*32+m*16+lk*4+r, permuted cols (u16x4 = 8B/lane)
    #pragma unroll
    for (int m = 0; m < 2; ++m) {
      #pragma unroll
      for (int r = 0; r < 4; ++r) {
        int rowg = n0 + s * 32 + m * 16 + lk * 4 + r;
        if (rowg < NN) {
          u16x4 v;
          #pragma unroll
          for (int n = 0; n < 4; ++n)
            v[n] = __builtin_bit_cast(unsigned short, __float2bfloat16(acc[m][n][r]));
          *(u16x4*)(Yb + (size_t)rowg * 512 + h * 256 + wid * 64 + lr * 4) = v;
        }
      }
    }
  }
}

// One wave per node: out[n] = deg[n]*(Y1b[n]+b) + sum_{CSR} Y2b[j].
// Yb is column-permuted; accumulate permuted, unpermute via 1KB/wave LDS.
__global__ __launch_bounds__(256) void k_epi(
    const unsigned short* __restrict__ Yb, const int* __restrict__ offs,
    const int* __restrict__ deg, const int* __restrict__ edst,
    const float* __restrict__ bias, float* __restrict__ out) {
  __shared__ float sm[1024];
  int wid = threadIdx.x >> 6;
  int lane = threadIdx.x & 63;
  int n = blockIdx.x * 4 + wid;
  if (n >= NN) return;
  int o = offs[n];
  int c = deg[n];
  const unsigned short* Y2 = Yb + 256 + (size_t)lane * 4;
  f32x4 a0 = {0.f,0.f,0.f,0.f}, a1 = a0, a2 = a0, a3 = a0, a4 = a0, a5 = a0, a6 = a0, a7 = a0;
  int e = 0;
  for (; e + 8 <= c; e += 8) {
    int j0 = edst[o+e],   j1 = edst[o+e+1], j2 = edst[o+e+2], j3 = edst[o+e+3];
    int j4 = edst[o+e+4], j5 = edst[o+e+5], j6 = edst[o+e+6], j7 = edst[o+e+7];
    u16x4 v0 = *(const u16x4*)(Y2 + (size_t)j0 * 512);
    u16x4 v1 = *(const u16x4*)(Y2 + (size_t)j1 * 512);
    u16x4 v2 = *(const u16x4*)(Y2 + (size_t)j2 * 512);
    u16x4 v3 = *(const u16x4*)(Y2 + (size_t)j3 * 512);
    u16x4 v4 = *(const u16x4*)(Y2 + (size_t)j4 * 512);
    u16x4 v5 = *(const u16x4*)(Y2 + (size_t)j5 * 512);
    u16x4 v6 = *(const u16x4*)(Y2 + (size_t)j6 * 512);
    u16x4 v7 = *(const u16x4*)(Y2 + (size_t)j7 * 512);
    #pragma unroll
    for (int i = 0; i < 4; ++i) {
      a0[i] += bf2f(v0[i]); a1[i] += bf2f(v1[i]); a2[i] += bf2f(v2[i]); a3[i] += bf2f(v3[i]);
      a4[i] += bf2f(v4[i]); a5[i] += bf2f(v5[i]); a6[i] += bf2f(v6[i]); a7[i] += bf2f(v7[i]);
    }
  }
  if (e + 4 <= c) {
    int j0 = edst[o+e], j1 = edst[o+e+1], j2 = edst[o+e+2], j3 = edst[o+e+3];
    u16x4 v0 = *(const u16x4*)(Y2 + (size_t)j0 * 512);
    u16x4 v1 = *(const u16x4*)(Y2 + (size_t)j1 * 512);
    u16x4 v2 = *(const u16x4*)(Y2 + (size_t)j2 * 512);
    u16x4 v3 = *(const u16x4*)(Y2 + (size_t)j3 * 512);
    #pragma unroll
    for (int i = 0; i < 4; ++i) {
      a0[i] += bf2f(v0[i]); a1[i] += bf2f(v1[i]); a2[i] += bf2f(v2[i]); a3[i] += bf2f(v3[i]);
    }
    e += 4;
  }
  if (e + 2 <= c) {
    int j0 = edst[o+e], j1 = edst[o+e+1];
    u16x4 v0 = *(const u16x4*)(Y2 + (size_t)j0 * 512);
    u16x4 v1 = *(const u16x4*)(Y2 + (size_t)j1 * 512);
    #pragma unroll
    for (int i = 0; i < 4; ++i) { a0[i] += bf2f(v0[i]); a1[i] += bf2f(v1[i]); }
    e += 2;
  }
  if (e < c) {
    int j0 = edst[o+e];
    u16x4 v0 = *(const u16x4*)(Y2 + (size_t)j0 * 512);
    #pragma unroll
    for (int i = 0; i < 4; ++i) a0[i] += bf2f(v0[i]);
  }
  u16x4 y1 = *(const u16x4*)(Yb + (size_t)n * 512 + lane * 4);
  float dg = (float)c;
  float* Wm = sm + wid * 256;
  #pragma unroll
  for (int i = 0; i < 4; ++i) {
    int p = lane * 4 + i;                               // permuted pos in half
    int tc = (p & 192) + ((p & 3) << 4) + ((p >> 2) & 15);  // true col in half
    float as = ((a0[i] + a1[i]) + (a2[i] + a3[i])) + ((a4[i] + a5[i]) + (a6[i] + a7[i]));
    Wm[tc] = dg * (bf2f(y1[i]) + bias[tc]) + as;
  }
  asm volatile("s_waitcnt lgkmcnt(0)" ::: "memory");   // wave-lockstep unpermute
  f32x4 res = *(const f32x4*)(Wm + lane * 4);
  __builtin_nontemporal_store(res, (f32x4*)out + (size_t)n * 64 + lane);
}

extern "C" void kernel_launch(void* const* d_in, const int* in_sizes, int n_in,
                              void* d_out, int out_size, void* d_ws, size_t ws_size,
                              hipStream_t stream) {
  const float* x = (const float*)d_in[0];
  const float* W = (const float*)d_in[1];
  const float* b = (const float*)d_in[2];
  const int* Ai = (const int*)d_in[3];
  const int* Aj = (const int*)d_in[4];
  float* out = (float*)d_out;

  int* ip = (int*)d_ws;
  int* deg    = ip;            // 50048 (zeroed by k_wz, padded)
  int* incl   = ip + 50048;
  int* offs   = ip + 100096;
  int* cursor = ip + 150144;
  int* bsum   = ip + 200192;   // 256
  int* edst   = ip + 200448;   // 312576
  unsigned short* WbP = (unsigned short*)(ip + 513024);   // 131072 bf16 = 256KB
  unsigned short* Yb  = (unsigned short*)(ip + 578560);   // 50048*512 bf16 = 51.2MB

  k_wz<<<260, 256, 0, stream>>>(W, WbP, deg);
  k_hist<<<1221, 256, 0, stream>>>(Ai, deg);
  k_scan1<<<196, 256, 0, stream>>>(deg, incl, bsum);
  k_scan2<<<1, 256, 0, stream>>>(bsum);
  k_scan3<<<196, 256, 0, stream>>>(incl, deg, bsum, offs, cursor);
  k_scatter<<<1221, 256, 0, stream>>>(Ai, Aj, cursor, edst);
  k_gemm<<<dim3(391, 2), 256, 0, stream>>>(x, WbP, Yb);
  k_epi<<<12500, 256, 0, stream>>>(Yb, offs, deg, edst, b, out);
}